// Round 1
// baseline (50.371 us; speedup 1.0000x reference)
//
#include <hip/hip_runtime.h>

#define D_MODEL   256
#define NUM_TYPES 7
#define BATCH     2
#define NLANES    512

// ---------------- Kernel 1: H = [x@W1a + b1 | x@W1b] ----------------
// H is (1024 x 512) fp32 in workspace. Cols 0..255 = hi (+b1), 256..511 = hj.
#define K1_ROWS 16
#define K1_COLS 128

__global__ __launch_bounds__(256) void k_h_gemm(
    const float* __restrict__ x, const float* __restrict__ W1,
    const float* __restrict__ b1, float* __restrict__ H)
{
    __shared__ float xs[K1_ROWS][D_MODEL];   // 16 KB
    const int tid = threadIdx.x;
    const int c0  = blockIdx.x * K1_COLS;
    const int r0  = blockIdx.y * K1_ROWS;

    // stage 16 rows of x (16*256 floats = 1024 float4)
    {
        const float4* src = (const float4*)(x + (size_t)r0 * D_MODEL);
        float4* dst = (float4*)(&xs[0][0]);
        #pragma unroll
        for (int q = 0; q < 4; ++q)
            dst[tid + q * 256] = src[tid + q * 256];
    }
    __syncthreads();

    const int c  = c0 + (tid & (K1_COLS - 1));  // global output col 0..511
    const int rg = tid >> 7;                     // 0..1 (8 rows each)

    // W element (k, c): c<256 -> W1[k][c] ; c>=256 -> W1[256+k][c-256]
    const float* Wb = (c < D_MODEL)
        ? (W1 + c)
        : (W1 + (size_t)D_MODEL * D_MODEL + (c - D_MODEL));

    float acc[8];
    #pragma unroll
    for (int rr = 0; rr < 8; ++rr) acc[rr] = 0.f;

    #pragma unroll 4
    for (int k = 0; k < D_MODEL; ++k) {
        const float w = Wb[(size_t)k * D_MODEL];
        #pragma unroll
        for (int rr = 0; rr < 8; ++rr)
            acc[rr] = fmaf(xs[rg * 8 + rr][k], w, acc[rr]);
    }

    const float bias = (c < D_MODEL) ? b1[c] : 0.f;
    #pragma unroll
    for (int rr = 0; rr < 8; ++rr)
        H[(size_t)(r0 + rg * 8 + rr) * 512 + c] = acc[rr] + bias;
}

// ---------------- Kernel 2: out[b,i,j,:] = relu(Hi[i]+Hj[j]) @ W2 + b2 ----------------
#define TI  32
#define TJ  32
#define KC  128      // K chunk staged in LDS
#define LDH 132      // padded LDS row stride (floats): rows 16 apart -> distinct bank groups

__global__ __launch_bounds__(256) void k_pair(
    const float* __restrict__ H, const float* __restrict__ W2,
    const float* __restrict__ b2, float* __restrict__ out)
{
    __shared__ float his[TI][LDH];   // 16.5 KB
    __shared__ float hjs[TJ][LDH];   // 16.5 KB

    const int tid = threadIdx.x;
    const int b   = blockIdx.z;
    const int i0  = blockIdx.y * TI;
    const int j0  = blockIdx.x * TJ;
    const int ti  = tid & 15;        // i rows: ti, ti+16
    const int tj  = tid >> 4;        // j rows: tj, tj+16

    float acc[2][2][NUM_TYPES];
    #pragma unroll
    for (int a = 0; a < 2; ++a)
        #pragma unroll
        for (int c = 0; c < 2; ++c)
            #pragma unroll
            for (int t = 0; t < NUM_TYPES; ++t) acc[a][c][t] = 0.f;

    for (int kc = 0; kc < D_MODEL / KC; ++kc) {
        __syncthreads();
        // stage Hi/Hj chunk: 32 rows x 128 floats = 1024 float4 each
        #pragma unroll
        for (int q = 0; q < 4; ++q) {
            const int f  = tid + q * 256;   // float4 index 0..1023
            const int r  = f >> 5;          // row 0..31
            const int kk = (f & 31) << 2;   // float offset in chunk
            const float4 vi = *(const float4*)(
                H + (size_t)(b * NLANES + i0 + r) * 512 + kc * KC + kk);
            *(float4*)&his[r][kk] = vi;
            const float4 vj = *(const float4*)(
                H + (size_t)(b * NLANES + j0 + r) * 512 + D_MODEL + kc * KC + kk);
            *(float4*)&hjs[r][kk] = vj;
        }
        __syncthreads();

        #pragma unroll 2
        for (int k4 = 0; k4 < KC; k4 += 4) {
            const float4 hi0 = *(const float4*)&his[ti][k4];
            const float4 hi1 = *(const float4*)&his[ti + 16][k4];
            const float4 hj0 = *(const float4*)&hjs[tj][k4];
            const float4 hj1 = *(const float4*)&hjs[tj + 16][k4];
            // uniform address -> scalar/L1 loads, 28 contiguous floats
            const float* w2p = W2 + (size_t)(kc * KC + k4) * NUM_TYPES;
            #pragma unroll
            for (int kk = 0; kk < 4; ++kk) {
                const float x0 = ((const float*)&hi0)[kk];
                const float x1 = ((const float*)&hi1)[kk];
                const float y0 = ((const float*)&hj0)[kk];
                const float y1 = ((const float*)&hj1)[kk];
                const float a00 = fmaxf(x0 + y0, 0.f);
                const float a01 = fmaxf(x0 + y1, 0.f);
                const float a10 = fmaxf(x1 + y0, 0.f);
                const float a11 = fmaxf(x1 + y1, 0.f);
                #pragma unroll
                for (int t = 0; t < NUM_TYPES; ++t) {
                    const float w = w2p[kk * NUM_TYPES + t];
                    acc[0][0][t] = fmaf(a00, w, acc[0][0][t]);
                    acc[0][1][t] = fmaf(a01, w, acc[0][1][t]);
                    acc[1][0][t] = fmaf(a10, w, acc[1][0][t]);
                    acc[1][1][t] = fmaf(a11, w, acc[1][1][t]);
                }
            }
        }
    }

    float bb[NUM_TYPES];
    #pragma unroll
    for (int t = 0; t < NUM_TYPES; ++t) bb[t] = b2[t];

    #pragma unroll
    for (int a = 0; a < 2; ++a) {
        const int gi = i0 + ti + a * 16;
        #pragma unroll
        for (int c = 0; c < 2; ++c) {
            const int gj = j0 + tj + c * 16;
            float* op = out + ((size_t)(b * NLANES + gi) * NLANES + gj) * NUM_TYPES;
            #pragma unroll
            for (int t = 0; t < NUM_TYPES; ++t)
                op[t] = acc[a][c][t] + bb[t];
        }
    }
}

extern "C" void kernel_launch(void* const* d_in, const int* in_sizes, int n_in,
                              void* d_out, int out_size, void* d_ws, size_t ws_size,
                              hipStream_t stream) {
    const float* x  = (const float*)d_in[0];   // (2,512,256)
    const float* W1 = (const float*)d_in[1];   // (512,256)
    const float* b1 = (const float*)d_in[2];   // (256)
    const float* W2 = (const float*)d_in[3];   // (256,7)
    const float* b2 = (const float*)d_in[4];   // (7)
    float* out = (float*)d_out;                // (2,512,512,7) fp32
    float* H   = (float*)d_ws;                 // 1024*512 floats = 2 MB

    // Kernel 1: 512 cols / 128 = 4 col-tiles, 1024 rows / 16 = 64 row-tiles
    k_h_gemm<<<dim3(4, 64), 256, 0, stream>>>(x, W1, b1, H);

    // Kernel 2: (j-tiles, i-tiles, batch)
    k_pair<<<dim3(NLANES / TJ, NLANES / TI, BATCH), 256, 0, stream>>>(H, W2, b2, out);
}